// Round 13
// baseline (3366.225 us; speedup 1.0000x reference)
//
#include <hip/hip_runtime.h>
#include <math.h>

#define B_ 1024
#define T_ 128
#define H_ 2048
#define C_ 10

typedef __bf16 bf16_t;
typedef __bf16 bf16x8 __attribute__((ext_vector_type(8)));
typedef __bf16 bf16x4 __attribute__((ext_vector_type(4)));
typedef float f32x4 __attribute__((ext_vector_type(4)));

// Static device storage: bf16 h ping-pong (8 MB), bf16 W_hh^T (8 MB),
// per-(t,bm) readiness counters (XCD-local handoff).
__device__ __align__(16) bf16_t g_hb[2][(size_t)B_ * H_];
__device__ __align__(16) bf16_t g_whhT[(size_t)H_ * H_];
__device__ int g_cnt[T_ * 8];   // [t][bm]; t=0 seeded to 32 by rnn_init

// AUX: cache policy. 0 = default; 1 = sc0 (force L1 miss -> read XCD L2).
template <int AUX>
__device__ __forceinline__ void gload16(const bf16_t* g, bf16_t* l) {
    __builtin_amdgcn_global_load_lds(
        (const __attribute__((address_space(1))) void*)g,
        (__attribute__((address_space(3))) void*)l, 16, 0, AUX);
}

// Counted-vmcnt barrier: retire oldest pipeline stage without draining.
template <int VM>
__device__ __forceinline__ void wait_vm_barrier() {
    asm volatile("s_waitcnt vmcnt(%0)\n\ts_barrier" :: "n"(VM) : "memory");
}

// One-time: W_hhT[n][k] = bf16(W_hh[k][n]) — B operand must be K-contiguous.
__global__ __launch_bounds__(256) void prep_whhT(const float* __restrict__ Whh) {
    __shared__ float tile[32][33];
    const int i  = threadIdx.x >> 3;
    const int j4 = (threadIdx.x & 7) * 4;
    const int r0 = blockIdx.y * 32;
    const int c0 = blockIdx.x * 32;
    f32x4 v = *(const f32x4*)(Whh + (size_t)(r0 + i) * H_ + c0 + j4);
    tile[i][j4 + 0] = v[0]; tile[i][j4 + 1] = v[1];
    tile[i][j4 + 2] = v[2]; tile[i][j4 + 3] = v[3];
    __syncthreads();
    bf16x4 o;
#pragma unroll
    for (int r = 0; r < 4; ++r) o[r] = (bf16_t)tile[j4 + r][i];
    *(bf16x4*)&g_whhT[(size_t)(c0 + i) * H_ + r0 + j4] = o;
}

// t = 0: h = tanh(x[:,0]*W_hx + b_h); also (re)initialize the counters.
__global__ __launch_bounds__(256) void rnn_init(const float* __restrict__ x,
                                                const float* __restrict__ Whx,
                                                const float* __restrict__ bh) {
    if (blockIdx.x == 0) {
        for (int i = threadIdx.x; i < T_ * 8; i += 256)
            g_cnt[i] = (i < 8) ? 32 : 0;   // g_cnt[0][*] = 32 (h0 ready)
    }
    const int gid = blockIdx.x * 256 + threadIdx.x;
    const int row = gid >> 9;
    const int col = (gid & 511) << 2;
    const float xv = x[(size_t)row * T_];
    f32x4 w = *(const f32x4*)&Whx[col];
    f32x4 b = *(const f32x4*)&bh[col];
    bf16x4 o;
#pragma unroll
    for (int j = 0; j < 4; ++j) o[j] = (bf16_t)tanhf(fmaf(xv, w[j], b[j]));
    *(bf16x4*)&g_hb[0][(size_t)row * H_ + col] = o;
}

// Persistent RNN, XCD-local sync (r10) + B-in-registers K-loop:
// B (W_hh^T) fragments are loaded DIRECTLY global->VGPR (static per-lane
// addresses, 16 B each), 4-slot register rotation, issued 3 iters ahead --
// no LDS staging and no ds_read for B at all. Only A uses the LDS ring
// (4 stages). Interleaved FIFO [B(u+3), A(u+3)] per iter gives a uniform
// steady wait of vmcnt(16) (4 load-groups in flight); tail 16/8/0.
// Map bm = li&7 = XCD: cross-step coherence lives in that XCD's L2
// (writers drain stores, relaxed agent atomic publish; readers sc0-stage A).
// Zig-zag K order keeps the L2/L1 tail of B hot across steps.
__global__ __launch_bounds__(256, 1) void rnn_persist(const float* __restrict__ x,
                                                      const float* __restrict__ Whx,
                                                      const float* __restrict__ bh) {
    extern __shared__ __align__(16) bf16_t smem[];
    bf16_t* As = smem;                 // 4 stages x 8192 elems (16 KB each)

    const int tid  = threadIdx.x;
    const int lane = tid & 63;
    const int wave = tid >> 6;
    const int li  = blockIdx.x;
    const int bm  = li & 7;                          // == XCD (blk%8 map)
    const int bn  = li >> 3;                         // 0..31

    const int wm = (wave & 1) * 64, wn = (wave >> 1) * 32;
    const int fr = lane & 15, fq = lane >> 4;

    // A staging: linear slot s holds row s>>3, lds-chunk s&7;
    // global chunk = (s&7) ^ (row&7)  (8-row spread -> 2-way frag reads).
    const int rA = tid >> 3;                         // 0..31
    const int cg = (tid & 7) ^ (rA & 7);
    const size_t aofsg = (size_t)(bm * 128 + rA) * H_ + cg * 8;
    // B fragment base addresses (per-lane, step-invariant up to koff):
    // col = bn*64 + wn + j*16 + fr, k = fq*8 (+cc*32 via offset:64)
    const size_t bof0 = (size_t)(bn * 64 + wn + fr) * H_ + fq * 8;
    const size_t bof1 = (size_t)(bn * 64 + wn + 16 + fr) * H_ + fq * 8;

#define ISSUE_A(SLOT)                                                    \
    do {                                                                 \
        gload16<1>(gpa,            As + (SLOT) * 8192 + tid * 8);        \
        gload16<1>(gpa + 32 * H_,  As + (SLOT) * 8192 + (tid + 256) * 8);\
        gload16<1>(gpa + 64 * H_,  As + (SLOT) * 8192 + (tid + 512) * 8);\
        gload16<1>(gpa + 96 * H_,  As + (SLOT) * 8192 + (tid + 768) * 8);\
        gpa += kstep;                                                    \
    } while (0)

// B-frag direct loads into the 4-slot register ring (4 loads/wave).
#define BLOAD(S)                                                         \
    do {                                                                 \
        asm volatile("global_load_dwordx4 %0, %2, off\n\t"               \
                     "global_load_dwordx4 %1, %2, off offset:64"         \
                     : "=&v"(bsl[S][0][0]), "=&v"(bsl[S][0][1])          \
                     : "v"(gbf0) : "memory");                            \
        asm volatile("global_load_dwordx4 %0, %2, off\n\t"               \
                     "global_load_dwordx4 %1, %2, off offset:64"         \
                     : "=&v"(bsl[S][1][0]), "=&v"(bsl[S][1][1])          \
                     : "v"(gbf1) : "memory");                            \
        gbf0 += kstep; gbf1 += kstep;                                    \
    } while (0)

    // A-frag LDS offsets: row*64 + ((cc*4+fq) ^ (row&7))*8; row&7 == fr&7.
    const int xr0 = (fq ^ (fr & 7)) * 8;
    const int xr1 = ((4 + fq) ^ (fr & 7)) * 8;
    int aoff[4][2];
#pragma unroll
    for (int i = 0; i < 4; ++i) {
        aoff[i][0] = (wm + i * 16 + fr) * 64 + xr0;
        aoff[i][1] = (wm + i * 16 + fr) * 64 + xr1;
    }

#define COMPUTE(S)                                                          \
    {                                                                       \
        _Pragma("unroll")                                                   \
        for (int cc = 0; cc < 2; ++cc) {                                    \
            bf16x8 af[4];                                                   \
            _Pragma("unroll")                                               \
            for (int i = 0; i < 4; ++i)                                     \
                af[i] = *(const bf16x8*)(As + (S) * 8192 + aoff[i][cc]);    \
            _Pragma("unroll")                                               \
            for (int i = 0; i < 4; ++i) {                                   \
                acc[i][0] = __builtin_amdgcn_mfma_f32_16x16x32_bf16(        \
                    af[i], bsl[S][0][cc], acc[i][0], 0, 0, 0);              \
                acc[i][1] = __builtin_amdgcn_mfma_f32_16x16x32_bf16(        \
                    af[i], bsl[S][1][cc], acc[i][1], 0, 0, 0);              \
            }                                                               \
        }                                                                   \
    }

    // epilogue constants (step-invariant)
    float wv[2], bv[2];
    int xbase[4];
#pragma unroll
    for (int j = 0; j < 2; ++j) {
        const int col = bn * 64 + wn + j * 16 + fr;
        wv[j] = Whx[col];
        bv[j] = bh[col];
    }
#pragma unroll
    for (int i = 0; i < 4; ++i)
        xbase[i] = (bm * 128 + wm + i * 16 + fq * 4) * T_;

    bf16x8 bsl[4][2][2];

    for (int t = 1; t < T_; ++t) {
        const bf16_t* __restrict__ Abuf = g_hb[(t - 1) & 1];
        bf16_t* __restrict__ hn = g_hb[t & 1];
        // zig-zag: odd steps walk K from the top (L1/L2 LRU tail is hot)
        const int odd   = t & 1;
        const int koff  = odd ? (H_ - 64) : 0;
        const int kstep = odd ? -64 : 64;
        const bf16_t* gpa  = Abuf + aofsg + koff;
        const bf16_t* gbf0 = g_whhT + bof0 + koff;
        const bf16_t* gbf1 = g_whhT + bof1 + koff;

        // wait until all 32 same-XCD writers of h-rows bm finished step t-1
        if (tid == 0) {
            while (__hip_atomic_load(&g_cnt[(t - 1) * 8 + bm], __ATOMIC_RELAXED,
                                     __HIP_MEMORY_SCOPE_AGENT) != 32)
                __builtin_amdgcn_s_sleep(2);
        }
        __syncthreads();          // no agent fence: sc0 A-loads read fresh L2

        f32x4 acc[4][2];
#pragma unroll
        for (int i = 0; i < 4; ++i)
#pragma unroll
            for (int j = 0; j < 2; ++j) acc[i][j] = (f32x4)(0.f);

        // prologue (interleaved so need-at-u retires exactly thru As(u)):
        // FIFO: [B0 A0 B1 A1 B2 A2]; per-iter append [B(u+3) A(u+3)].
        BLOAD(0); ISSUE_A(0);
        BLOAD(1); ISSUE_A(1);
        BLOAD(2); ISSUE_A(2);

        // it0 (issue stage 3)
        wait_vm_barrier<16>(); BLOAD(3); ISSUE_A(3); COMPUTE(0);
        // its 1..28: steady vmcnt(16), slot rotation mod 4
        for (int g = 0; g < 7; ++g) {
#pragma unroll
            for (int k = 0; k < 4; ++k) {
                wait_vm_barrier<16>();
                BLOAD(k);
                ISSUE_A(k);
                COMPUTE((k + 1) & 3);
            }
        }
        // its 29..31: drain (queue 24 -> 16 -> 8 -> 0)
        wait_vm_barrier<16>(); COMPUTE(1);
        wait_vm_barrier<8>();  COMPUTE(2);
        wait_vm_barrier<0>();  COMPUTE(3);

        // epilogue: + x_t*W_hx + b_h, tanh, bf16 store
#pragma unroll
        for (int i = 0; i < 4; ++i) {
            const int row0 = bm * 128 + wm + i * 16 + fq * 4;
            float xv[4];
#pragma unroll
            for (int r = 0; r < 4; ++r) xv[r] = x[xbase[i] + r * T_ + t];
#pragma unroll
            for (int j = 0; j < 2; ++j) {
                const int col = bn * 64 + wn + j * 16 + fr;
#pragma unroll
                for (int r = 0; r < 4; ++r)
                    hn[(size_t)(row0 + r) * H_ + col] =
                        (bf16_t)tanhf(acc[i][j][r] + xv[r] * wv[j] + bv[j]);
            }
        }

        // publish: drain stores to L2, join waves, bump counter.
        asm volatile("s_waitcnt vmcnt(0)" ::: "memory");
        __syncthreads();
        if (tid == 0)
            __hip_atomic_fetch_add(&g_cnt[t * 8 + bm], 1, __ATOMIC_RELAXED,
                                   __HIP_MEMORY_SCOPE_AGENT);
    }
#undef COMPUTE
#undef BLOAD
#undef ISSUE_A
}

// p = h_T @ W_ph + b_p : one wave per batch row, fp32 accumulate.
__global__ __launch_bounds__(64) void rnn_proj(const float* __restrict__ Wph,
                                               const float* __restrict__ bp,
                                               float* __restrict__ out, int sb) {
    const int b = blockIdx.x;
    const int l = threadIdx.x;
    const bf16_t* h = g_hb[sb] + (size_t)b * H_;
    float acc[C_];
#pragma unroll
    for (int c = 0; c < C_; ++c) acc[c] = 0.f;
    for (int k = l; k < H_; k += 64) {
        const float hv = (float)h[k];
#pragma unroll
        for (int c = 0; c < C_; ++c)
            acc[c] = fmaf(hv, Wph[k * C_ + c], acc[c]);
    }
#pragma unroll
    for (int off = 32; off > 0; off >>= 1)
#pragma unroll
        for (int c = 0; c < C_; ++c) acc[c] += __shfl_down(acc[c], off);
    if (l == 0) {
#pragma unroll
        for (int c = 0; c < C_; ++c) out[b * C_ + c] = acc[c] + bp[c];
    }
}

extern "C" void kernel_launch(void* const* d_in, const int* in_sizes, int n_in,
                              void* d_out, int out_size, void* d_ws, size_t ws_size,
                              hipStream_t stream) {
    const float* x   = (const float*)d_in[0];   // [1024,128]
    const float* Whx = (const float*)d_in[1];   // [1,2048]
    const float* Whh = (const float*)d_in[2];   // [2048,2048]
    const float* bh  = (const float*)d_in[3];   // [2048]
    const float* Wph = (const float*)d_in[4];   // [2048,10]
    const float* bp  = (const float*)d_in[5];   // [1,10]
    float* out = (float*)d_out;                 // [1024,10]

    static bool attr_set = false;
    if (!attr_set) {
        hipFuncSetAttribute((const void*)rnn_persist,
                            hipFuncAttributeMaxDynamicSharedMemorySize, 98304);
        attr_set = true;
    }

    prep_whhT<<<dim3(64, 64), 256, 0, stream>>>(Whh);
    rnn_init<<<(B_ * H_ / 4) / 256, 256, 0, stream>>>(x, Whx, bh);
    // 98304 B dynamic LDS (> 80 KB) forces 1 block/CU -> the blk%8 = XCD
    // mapping and all-blocks-co-resident spin assumption hold.
    rnn_persist<<<256, 256, 98304, stream>>>(x, Whx, bh);
    rnn_proj<<<B_, 64, 0, stream>>>(Wph, bp, out, (T_ - 1) & 1);
}